// Round 11
// baseline (484.408 us; speedup 1.0000x reference)
//
#include <hip/hip_runtime.h>
#include <hip/hip_bf16.h>
#include <math.h>

#define T 2048
#define C 2048
#define NH 16
#define HD 128
#define SCALE 0.08838834764831845f   // 1/sqrt(128)
#define WL_CAP 2048
#define MARG 1e-4f                    // |sig*1.99-1| margin ~ |z-z*|<2e-4

typedef short s16x8 __attribute__((ext_vector_type(8)));
typedef float f32x4 __attribute__((ext_vector_type(4)));
typedef _Float16 f16;
typedef f16 f16x8 __attribute__((ext_vector_type(8)));
typedef unsigned int u32;

__device__ __forceinline__ float wave_sum(float v) {
  #pragma unroll
  for (int o = 32; o > 0; o >>= 1) v += __shfl_xor(v, o, 64);
  return v;
}
// RNE fp32->bf16
__device__ __forceinline__ unsigned short f2bf(float f) {
  unsigned u = __float_as_uint(f);
  u += 0x7FFFu + ((u >> 16) & 1u);
  return (unsigned short)(u >> 16);
}

// async global->LDS 16B copy; dest must be linear in lane (base + lane*16)
__device__ __forceinline__ void gld16(const void* g, void* l) {
  __builtin_amdgcn_global_load_lds(
      (const __attribute__((address_space(1))) u32*)g,
      (__attribute__((address_space(3))) u32*)l, 16, 0, 0);
}

// ---------------- fp32 -> bf16 pre-convert (fallback path only) ----------
__global__ __launch_bounds__(256) void to_bf16(const float* __restrict__ in,
                                               unsigned short* __restrict__ outp,
                                               int n4) {
  int i = blockIdx.x * blockDim.x + threadIdx.x;
  const int stride = gridDim.x * blockDim.x;
  for (; i < n4; i += stride) {
    float4 v = ((const float4*)in)[i];
    ushort4 o;
    o.x = f2bf(v.x); o.y = f2bf(v.y); o.z = f2bf(v.z); o.w = f2bf(v.w);
    ((ushort4*)outp)[i] = o;
  }
}

// ---------------- shared split constants ----------------
#define PRESC 4096.0f               // 2^12
#define S0F 5.9604644775390625e-8f  // 2^-24
#define S1F 2.9103830456733704e-11f // 2^-35
#define S2F 1.4210854715202004e-14f // 2^-46

__device__ __forceinline__ void split4(float4 v, ushort4& hi, ushort4& lo) {
  float s0 = v.x * PRESC, s1 = v.y * PRESC, s2 = v.z * PRESC, s3 = v.w * PRESC;
  union { f16 h[4]; ushort4 u; } H, L;
  H.h[0] = (f16)s0; H.h[1] = (f16)s1; H.h[2] = (f16)s2; H.h[3] = (f16)s3;
  L.h[0] = (f16)((s0 - (float)H.h[0]) * 2048.0f);
  L.h[1] = (f16)((s1 - (float)H.h[1]) * 2048.0f);
  L.h[2] = (f16)((s2 - (float)H.h[2]) * 2048.0f);
  L.h[3] = (f16)((s3 - (float)H.h[3]) * 2048.0f);
  hi = H.u; lo = L.u;
}

// ---------------- fp32 -> fp16 hi/lo pre-split (fallback single) ----------
__global__ __launch_bounds__(256) void split_f16(const float* __restrict__ in,
                                                 unsigned short* __restrict__ hip_,
                                                 unsigned short* __restrict__ lop,
                                                 int n4) {
  int i = blockIdx.x * blockDim.x + threadIdx.x;
  const int stride = gridDim.x * blockDim.x;
  for (; i < n4; i += stride) {
    ushort4 h, l;
    split4(((const float4*)in)[i], h, l);
    ((ushort4*)hip_)[i] = h;
    ((ushort4*)lop)[i] = l;
  }
}

// ---------------- fused pre-split of x, Wq, Wk (1 launch) -----------------
// NOTE: does NOT touch ctr — ctr lives inside the wkl region and must be
// zeroed AFTER this kernel completes (separate zero_ctr launch).
__global__ __launch_bounds__(256) void pre_split3(const float* __restrict__ x,
                                                  const float* __restrict__ Wq,
                                                  const float* __restrict__ Wk,
                                                  unsigned short* __restrict__ xh,
                                                  unsigned short* __restrict__ xl,
                                                  unsigned short* __restrict__ wqh,
                                                  unsigned short* __restrict__ wql,
                                                  unsigned short* __restrict__ wkh,
                                                  unsigned short* __restrict__ wkl,
                                                  int n4) {
  const float* __restrict__ in;
  unsigned short *oh, *ol;
  if (blockIdx.y == 0)      { in = x;  oh = xh;  ol = xl;  }
  else if (blockIdx.y == 1) { in = Wq; oh = wqh; ol = wql; }
  else                      { in = Wk; oh = wkh; ol = wkl; }
  int i = blockIdx.x * blockDim.x + threadIdx.x;
  const int stride = gridDim.x * blockDim.x;
  for (; i < n4; i += stride) {
    ushort4 h, l;
    split4(((const float4*)in)[i], h, l);
    ((ushort4*)oh)[i] = h;
    ((ushort4*)ol)[i] = l;
  }
}

// ---------------- fp32 -> fp16 hi plane only ----------
__global__ __launch_bounds__(256) void to_f16h(const float* __restrict__ in,
                                               unsigned short* __restrict__ outp,
                                               int n4) {
  int i = blockIdx.x * blockDim.x + threadIdx.x;
  const int stride = gridDim.x * blockDim.x;
  for (; i < n4; i += stride) {
    float4 v = ((const float4*)in)[i];
    union { f16 h[4]; ushort4 u; } H;
    H.h[0] = (f16)(v.x * PRESC); H.h[1] = (f16)(v.y * PRESC);
    H.h[2] = (f16)(v.z * PRESC); H.h[3] = (f16)(v.w * PRESC);
    ((ushort4*)outp)[i] = H.u;
  }
}

// ---------------- fused tail convert: Y and Wproj to fp16-hi --------------
__global__ __launch_bounds__(256) void post_h2(const float* __restrict__ Y,
                                               const float* __restrict__ Wproj,
                                               unsigned short* __restrict__ yh,
                                               unsigned short* __restrict__ wph,
                                               int n4) {
  const float* __restrict__ in = blockIdx.y ? Wproj : Y;
  unsigned short* __restrict__ outp = blockIdx.y ? wph : yh;
  int i = blockIdx.x * blockDim.x + threadIdx.x;
  const int stride = gridDim.x * blockDim.x;
  for (; i < n4; i += stride) {
    float4 v = ((const float4*)in)[i];
    union { f16 h[4]; ushort4 u; } H;
    H.h[0] = (f16)(v.x * PRESC); H.h[1] = (f16)(v.y * PRESC);
    H.h[2] = (f16)(v.z * PRESC); H.h[3] = (f16)(v.w * PRESC);
    ((ushort4*)outp)[i] = H.u;
  }
}

#define SBM 64
#define SBN 128
#define SBK 32

// ---------------- fused Q+K GEMM, 128x(64|64) tile, A shared --------------
// Staging via global_load_lds: linear LDS dest (tid*16B = wave base+lane*16),
// source column pre-swizzled by qg^((sr>>1)&3) — LDS image bit-identical to
// the round-9 reg-staged version (slot p holds chunk p^s), so fragments and
// the full FP sequence are unchanged => Q/K bit-identical.
__global__ __launch_bounds__(256, 2) void gemm_qkf(const unsigned short* __restrict__ xhp,
                                                   const unsigned short* __restrict__ xlp,
                                                   const unsigned short* __restrict__ wqh,
                                                   const unsigned short* __restrict__ wql,
                                                   const unsigned short* __restrict__ wkh,
                                                   const unsigned short* __restrict__ wkl,
                                                   float* __restrict__ Qo,
                                                   float* __restrict__ Ko) {
  __shared__ unsigned short Ah[2][128 * 32];   // 2 x 8 KB
  __shared__ unsigned short Av[2][128 * 32];
  __shared__ unsigned short Bh[2][128 * 32];   // rows 0-63 = Wq, 64-127 = Wk
  __shared__ unsigned short Bv[2][128 * 32];   // 64 KB total
  const int tid = threadIdx.x;
  const int bm = blockIdx.x * 128;
  const int bn = blockIdx.y * 64;      // col offset within each weight
  const int wv = tid >> 6, lane = tid & 63;
  const int wm = wv & 1, wn = wv >> 1;  // wn: 0=Q, 1=K
  const int lrow = lane & 15, lquad = lane >> 4;

  const int sr = tid >> 2, qg = tid & 3;
  const int qsw = qg ^ ((sr >> 1) & 3);   // pre-swizzled SOURCE chunk
  const int ld0 = tid * 8;                // linear LDS dest (ushort idx)
  const int ld1 = 2048 + tid * 8;         // row-block 1 (rows 64..127)

  const size_t arow0 = (size_t)(bm + sr) * C;
  const size_t arow1 = (size_t)(bm + 64 + sr) * C;
  const size_t brow  = (size_t)(bn + sr) * C;

  f32x4 acc0[4][4], acc1[4][4];
  #pragma unroll
  for (int i = 0; i < 4; ++i)
    #pragma unroll
    for (int j = 0; j < 4; ++j) {
      acc0[i][j] = (f32x4){0.f, 0.f, 0.f, 0.f};
      acc1[i][j] = (f32x4){0.f, 0.f, 0.f, 0.f};
    }

  // prologue: stage iter 0 into buffer 0
  {
    const int k0 = qsw * 8;
    gld16(xhp + arow0 + k0, &Ah[0][ld0]);
    gld16(xhp + arow1 + k0, &Ah[0][ld1]);
    gld16(xlp + arow0 + k0, &Av[0][ld0]);
    gld16(xlp + arow1 + k0, &Av[0][ld1]);
    gld16(wqh + brow + k0, &Bh[0][ld0]);
    gld16(wkh + brow + k0, &Bh[0][ld1]);
    gld16(wql + brow + k0, &Bv[0][ld0]);
    gld16(wkl + brow + k0, &Bv[0][ld1]);
  }
  __syncthreads();

  const int niter = C / 32;
  for (int it = 0; it < niter; ++it) {
    const int cur = it & 1;
    if (it + 1 < niter) {
      const int nxt = cur ^ 1;
      const int k0 = (it + 1) * 32 + qsw * 8;
      gld16(xhp + arow0 + k0, &Ah[nxt][ld0]);
      gld16(xhp + arow1 + k0, &Ah[nxt][ld1]);
      gld16(xlp + arow0 + k0, &Av[nxt][ld0]);
      gld16(xlp + arow1 + k0, &Av[nxt][ld1]);
      gld16(wqh + brow + k0, &Bh[nxt][ld0]);
      gld16(wkh + brow + k0, &Bh[nxt][ld1]);
      gld16(wql + brow + k0, &Bv[nxt][ld0]);
      gld16(wkl + brow + k0, &Bv[nxt][ld1]);
    }
    f16x8 ah[4], av[4], bh[4], bv[4];
    #pragma unroll
    for (int mi = 0; mi < 4; ++mi) {
      const int r = wm * 64 + mi * 16 + lrow;
      const int q = lquad ^ ((r >> 1) & 3);
      ah[mi] = *(const f16x8*)&Ah[cur][r * 32 + q * 8];
      av[mi] = *(const f16x8*)&Av[cur][r * 32 + q * 8];
    }
    #pragma unroll
    for (int ni = 0; ni < 4; ++ni) {
      const int r = wn * 64 + ni * 16 + lrow;
      const int q = lquad ^ ((r >> 1) & 3);
      bh[ni] = *(const f16x8*)&Bh[cur][r * 32 + q * 8];
      bv[ni] = *(const f16x8*)&Bv[cur][r * 32 + q * 8];
    }
    #pragma unroll
    for (int mi = 0; mi < 4; ++mi)
      #pragma unroll
      for (int ni = 0; ni < 4; ++ni) {
        acc0[mi][ni] = __builtin_amdgcn_mfma_f32_16x16x32_f16(ah[mi], bh[ni], acc0[mi][ni], 0, 0, 0);
        acc1[mi][ni] = __builtin_amdgcn_mfma_f32_16x16x32_f16(ah[mi], bv[ni], acc1[mi][ni], 0, 0, 0);
        acc1[mi][ni] = __builtin_amdgcn_mfma_f32_16x16x32_f16(av[mi], bh[ni], acc1[mi][ni], 0, 0, 0);
      }
    __syncthreads();
  }
  // epilogue: C/D layout col=lane&15, row=lquad*4+r (m89-verified)
  float* __restrict__ Cc = wn ? Ko : Qo;
  #pragma unroll
  for (int mi = 0; mi < 4; ++mi)
    #pragma unroll
    for (int ni = 0; ni < 4; ++ni)
      #pragma unroll
      for (int r = 0; r < 4; ++r) {
        int row = bm + wm * 64 + mi * 16 + lquad * 4 + r;
        int col = bn + ni * 16 + lrow;
        Cc[(size_t)row * C + col] = acc0[mi][ni][r] * S0F + acc1[mi][ni][r] * S1F;
      }
}

// ---------------- 1-term fp16-hi GEMM, dense 128x128 tile -----------------
// 4 waves x 64x64 out (16 MFMA per 8 ds_reads/wave); global_load_lds staging
// with pre-swizzled source. K ascending, 1 MFMA/(mi,ni)/iter => per-element
// FP sequence identical to the prior gemm_h1.
__global__ __launch_bounds__(256) void gemm_h1(const unsigned short* __restrict__ A,
                                               const unsigned short* __restrict__ B,
                                               float* __restrict__ Cc) {
  __shared__ unsigned short Ah[2][128 * 32];   // 2 x 8 KB
  __shared__ unsigned short Bh[2][128 * 32];   // 32 KB total
  const int tid = threadIdx.x;
  const int bm = blockIdx.x * 128;
  const int bn = blockIdx.y * 128;
  const int wv = tid >> 6, lane = tid & 63;
  const int wm = wv & 1, wn = wv >> 1;
  const int lrow = lane & 15, lquad = lane >> 4;

  const int sr = tid >> 2, qg = tid & 3;
  const int qsw = qg ^ ((sr >> 1) & 3);
  const int ld0 = tid * 8;
  const int ld1 = 2048 + tid * 8;

  const size_t arow0 = (size_t)(bm + sr) * C;
  const size_t arow1 = (size_t)(bm + 64 + sr) * C;
  const size_t brow0 = (size_t)(bn + sr) * C;
  const size_t brow1 = (size_t)(bn + 64 + sr) * C;

  f32x4 acc[4][4];
  #pragma unroll
  for (int i = 0; i < 4; ++i)
    #pragma unroll
    for (int j = 0; j < 4; ++j) acc[i][j] = (f32x4){0.f, 0.f, 0.f, 0.f};

  {
    const int k0 = qsw * 8;
    gld16(A + arow0 + k0, &Ah[0][ld0]);
    gld16(A + arow1 + k0, &Ah[0][ld1]);
    gld16(B + brow0 + k0, &Bh[0][ld0]);
    gld16(B + brow1 + k0, &Bh[0][ld1]);
  }
  __syncthreads();

  const int niter = C / 32;
  for (int it = 0; it < niter; ++it) {
    const int cur = it & 1;
    if (it + 1 < niter) {
      const int nxt = cur ^ 1;
      const int k0 = (it + 1) * 32 + qsw * 8;
      gld16(A + arow0 + k0, &Ah[nxt][ld0]);
      gld16(A + arow1 + k0, &Ah[nxt][ld1]);
      gld16(B + brow0 + k0, &Bh[nxt][ld0]);
      gld16(B + brow1 + k0, &Bh[nxt][ld1]);
    }
    f16x8 af[4], bf[4];
    #pragma unroll
    for (int mi = 0; mi < 4; ++mi) {
      const int r = wm * 64 + mi * 16 + lrow;
      const int q = lquad ^ ((r >> 1) & 3);
      af[mi] = *(const f16x8*)&Ah[cur][r * 32 + q * 8];
    }
    #pragma unroll
    for (int ni = 0; ni < 4; ++ni) {
      const int r = wn * 64 + ni * 16 + lrow;
      const int q = lquad ^ ((r >> 1) & 3);
      bf[ni] = *(const f16x8*)&Bh[cur][r * 32 + q * 8];
    }
    #pragma unroll
    for (int mi = 0; mi < 4; ++mi)
      #pragma unroll
      for (int ni = 0; ni < 4; ++ni)
        acc[mi][ni] = __builtin_amdgcn_mfma_f32_16x16x32_f16(af[mi], bf[ni], acc[mi][ni], 0, 0, 0);
    __syncthreads();
  }
  #pragma unroll
  for (int mi = 0; mi < 4; ++mi)
    #pragma unroll
    for (int ni = 0; ni < 4; ++ni)
      #pragma unroll
      for (int r = 0; r < 4; ++r) {
        int row = bm + wm * 64 + mi * 16 + lquad * 4 + r;
        int col = bn + wn * 64 + ni * 16 + lrow;
        Cc[(size_t)row * C + col] = acc[mi][ni][r] * S0F;
      }
}

// ---------------- Q/K GEMM with IN-KERNEL split (round-5 fallback) --------
__device__ __forceinline__ void split8(const float4 v0, const float4 v1,
                                       uint4& hi, uint4& lo) {
  float s[8] = {v0.x * PRESC, v0.y * PRESC, v0.z * PRESC, v0.w * PRESC,
                v1.x * PRESC, v1.y * PRESC, v1.z * PRESC, v1.w * PRESC};
  union { uint4 u; f16 h[8]; } H, L;
  #pragma unroll
  for (int i = 0; i < 8; ++i) {
    f16 h2 = (f16)s[i];
    float d = s[i] - (float)h2;
    H.h[i] = h2;
    L.h[i] = (f16)(d * 2048.0f);
  }
  hi = H.u; lo = L.u;
}

__global__ __launch_bounds__(256, 2) void gemm_qk_split16(const float* __restrict__ A,
                                                          const float* __restrict__ Wq,
                                                          const float* __restrict__ Wk,
                                                          float* __restrict__ Qo,
                                                          float* __restrict__ Ko) {
  const float* __restrict__ Bw = blockIdx.z ? Wk : Wq;
  float* __restrict__ Cc = blockIdx.z ? Ko : Qo;
  __shared__ unsigned short Ah[2][SBM * SBK];
  __shared__ unsigned short Av[2][SBM * SBK];
  __shared__ unsigned short Bh[2][SBN * SBK];
  __shared__ unsigned short Bv[2][SBN * SBK];
  const int tid = threadIdx.x;
  const int bm = blockIdx.x * SBM;
  const int bn = blockIdx.y * SBN;
  const int wv = tid >> 6, lane = tid & 63;
  const int wm = wv & 1, wn = wv >> 1;
  const int lrow = lane & 15, lquad = lane >> 4;

  const int a_row = tid >> 2, qg = tid & 3;
  const int a_qs = qg ^ ((a_row >> 1) & 3);
  const int b_row0 = tid >> 2;
  const int b_qs = qg ^ ((b_row0 >> 1) & 3);

  f32x4 acc[3][2][4];
  #pragma unroll
  for (int g = 0; g < 3; ++g)
    #pragma unroll
    for (int i = 0; i < 2; ++i)
      #pragma unroll
      for (int j = 0; j < 4; ++j) acc[g][i][j] = (f32x4){0.f, 0.f, 0.f, 0.f};

  {
    const float* pA  = A  + (size_t)(bm + a_row) * C + qg * 8;
    const float* pB0 = Bw + (size_t)(bn + b_row0) * C + qg * 8;
    const float* pB1 = Bw + (size_t)(bn + 64 + b_row0) * C + qg * 8;
    uint4 h, l;
    split8(*(const float4*)pA, *(const float4*)(pA + 4), h, l);
    *(uint4*)&Ah[0][a_row * SBK + a_qs * 8] = h;
    *(uint4*)&Av[0][a_row * SBK + a_qs * 8] = l;
    split8(*(const float4*)pB0, *(const float4*)(pB0 + 4), h, l);
    *(uint4*)&Bh[0][b_row0 * SBK + b_qs * 8] = h;
    *(uint4*)&Bv[0][b_row0 * SBK + b_qs * 8] = l;
    split8(*(const float4*)pB1, *(const float4*)(pB1 + 4), h, l);
    *(uint4*)&Bh[0][(64 + b_row0) * SBK + b_qs * 8] = h;
    *(uint4*)&Bv[0][(64 + b_row0) * SBK + b_qs * 8] = l;
  }
  __syncthreads();

  const int niter = C / SBK;
  for (int it = 0; it < niter; ++it) {
    const int cur = it & 1;
    const bool has = (it + 1) < niter;
    float4 a0n, a1n, b00n, b01n, b10n, b11n;
    if (has) {
      const int k0 = (it + 1) * SBK;
      const float* pA  = A  + (size_t)(bm + a_row) * C + k0 + qg * 8;
      const float* pB0 = Bw + (size_t)(bn + b_row0) * C + k0 + qg * 8;
      const float* pB1 = Bw + (size_t)(bn + 64 + b_row0) * C + k0 + qg * 8;
      a0n = *(const float4*)pA;   a1n = *(const float4*)(pA + 4);
      b00n = *(const float4*)pB0; b01n = *(const float4*)(pB0 + 4);
      b10n = *(const float4*)pB1; b11n = *(const float4*)(pB1 + 4);
    }
    f16x8 ah[2], av[2], bh[4], bv[4];
    #pragma unroll
    for (int mi = 0; mi < 2; ++mi) {
      const int r = wm * 32 + mi * 16 + lrow;
      const int q = lquad ^ ((r >> 1) & 3);
      ah[mi] = *(const f16x8*)&Ah[cur][r * SBK + q * 8];
      av[mi] = *(const f16x8*)&Av[cur][r * SBK + q * 8];
    }
    #pragma unroll
    for (int ni = 0; ni < 4; ++ni) {
      const int r = wn * 64 + ni * 16 + lrow;
      const int q = lquad ^ ((r >> 1) & 3);
      bh[ni] = *(const f16x8*)&Bh[cur][r * SBK + q * 8];
      bv[ni] = *(const f16x8*)&Bv[cur][r * SBK + q * 8];
    }
    #pragma unroll
    for (int mi = 0; mi < 2; ++mi)
      #pragma unroll
      for (int ni = 0; ni < 4; ++ni) {
        acc[0][mi][ni] = __builtin_amdgcn_mfma_f32_16x16x32_f16(ah[mi], bh[ni], acc[0][mi][ni], 0, 0, 0);
        acc[1][mi][ni] = __builtin_amdgcn_mfma_f32_16x16x32_f16(ah[mi], bv[ni], acc[1][mi][ni], 0, 0, 0);
        acc[1][mi][ni] = __builtin_amdgcn_mfma_f32_16x16x32_f16(av[mi], bh[ni], acc[1][mi][ni], 0, 0, 0);
        acc[2][mi][ni] = __builtin_amdgcn_mfma_f32_16x16x32_f16(av[mi], bv[ni], acc[2][mi][ni], 0, 0, 0);
      }
    if (has) {
      const int nxt = cur ^ 1;
      uint4 h, l;
      split8(a0n, a1n, h, l);
      *(uint4*)&Ah[nxt][a_row * SBK + a_qs * 8] = h;
      *(uint4*)&Av[nxt][a_row * SBK + a_qs * 8] = l;
      split8(b00n, b01n, h, l);
      *(uint4*)&Bh[nxt][b_row0 * SBK + b_qs * 8] = h;
      *(uint4*)&Bv[nxt][b_row0 * SBK + b_qs * 8] = l;
      split8(b10n, b11n, h, l);
      *(uint4*)&Bh[nxt][(64 + b_row0) * SBK + b_qs * 8] = h;
      *(uint4*)&Bv[nxt][(64 + b_row0) * SBK + b_qs * 8] = l;
    }
    __syncthreads();
  }
  #pragma unroll
  for (int mi = 0; mi < 2; ++mi)
    #pragma unroll
    for (int ni = 0; ni < 4; ++ni)
      #pragma unroll
      for (int r = 0; r < 4; ++r) {
        int row = bm + wm * 32 + mi * 16 + lquad * 4 + r;
        int col = bn + wn * 64 + ni * 16 + lrow;
        float v = acc[0][mi][ni][r] * S0F + (acc[1][mi][ni][r] * S1F + acc[2][mi][ni][r] * S2F);
        Cc[(size_t)row * C + col] = v;
      }
}

// ---------------- bf16 MFMA GEMM (fallback path only) ---------------------
#define VBM 64
#define VBN 128
#define VBK 32

__global__ __launch_bounds__(256) void gemm_bf16n(const unsigned short* __restrict__ A,
                                                  const unsigned short* __restrict__ B,
                                                  float* __restrict__ Cc) {
  __shared__ unsigned short Al[2][VBM * VBK];
  __shared__ unsigned short Bl[2][VBN * VBK];
  const int tid = threadIdx.x;
  const int bm = blockIdx.x * VBM;
  const int bn = blockIdx.y * VBN;
  const int wv = tid >> 6, lane = tid & 63;
  const int wm = wv & 1, wn = wv >> 1;
  const int lrow = lane & 15, lquad = lane >> 4;

  const int a_row = tid >> 2, qg = tid & 3;
  const int a_qs = qg ^ ((a_row >> 1) & 3);
  const int b_row0 = tid >> 2;
  const int b_qs = qg ^ ((b_row0 >> 1) & 3);

  f32x4 acc[2][4];
  #pragma unroll
  for (int i = 0; i < 2; ++i)
    #pragma unroll
    for (int j = 0; j < 4; ++j) acc[i][j] = (f32x4){0.f, 0.f, 0.f, 0.f};

  {
    uint4 av = *(const uint4*)(A + (size_t)(bm + a_row) * C + qg * 8);
    uint4 b0 = *(const uint4*)(B + (size_t)(bn + b_row0) * C + qg * 8);
    uint4 b1 = *(const uint4*)(B + (size_t)(bn + 64 + b_row0) * C + qg * 8);
    *(uint4*)&Al[0][a_row * VBK + a_qs * 8] = av;
    *(uint4*)&Bl[0][b_row0 * VBK + b_qs * 8] = b0;
    *(uint4*)&Bl[0][(64 + b_row0) * VBK + b_qs * 8] = b1;
  }
  __syncthreads();

  const int niter = C / VBK;
  for (int it = 0; it < niter; ++it) {
    const int cur = it & 1;
    const bool has = (it + 1) < niter;
    uint4 avn, b0n, b1n;
    if (has) {
      const int k0 = (it + 1) * VBK;
      avn = *(const uint4*)(A + (size_t)(bm + a_row) * C + k0 + qg * 8);
      b0n = *(const uint4*)(B + (size_t)(bn + b_row0) * C + k0 + qg * 8);
      b1n = *(const uint4*)(B + (size_t)(bn + 64 + b_row0) * C + k0 + qg * 8);
    }
    s16x8 af[2], bfr[4];
    #pragma unroll
    for (int mi = 0; mi < 2; ++mi) {
      const int r = wm * 32 + mi * 16 + lrow;
      const int q = lquad ^ ((r >> 1) & 3);
      af[mi] = *(const s16x8*)&Al[cur][r * VBK + q * 8];
    }
    #pragma unroll
    for (int ni = 0; ni < 4; ++ni) {
      const int r = wn * 64 + ni * 16 + lrow;
      const int q = lquad ^ ((r >> 1) & 3);
      bfr[ni] = *(const s16x8*)&Bl[cur][r * VBK + q * 8];
    }
    #pragma unroll
    for (int mi = 0; mi < 2; ++mi)
      #pragma unroll
      for (int ni = 0; ni < 4; ++ni)
        acc[mi][ni] = __builtin_amdgcn_mfma_f32_16x16x32_bf16(af[mi], bfr[ni], acc[mi][ni], 0, 0, 0);
    if (has) {
      const int nxt = cur ^ 1;
      *(uint4*)&Al[nxt][a_row * VBK + a_qs * 8] = avn;
      *(uint4*)&Bl[nxt][b_row0 * VBK + b_qs * 8] = b0n;
      *(uint4*)&Bl[nxt][(64 + b_row0) * VBK + b_qs * 8] = b1n;
    }
    __syncthreads();
  }
  #pragma unroll
  for (int mi = 0; mi < 2; ++mi)
    #pragma unroll
    for (int ni = 0; ni < 4; ++ni)
      #pragma unroll
      for (int r = 0; r < 4; ++r) {
        int row = bm + wm * 32 + mi * 16 + lquad * 4 + r;
        int col = bn + wn * 64 + ni * 16 + lrow;
        Cc[(size_t)row * C + col] = acc[mi][ni][r];
      }
}

// ---------------- zero worklist counter ----------------
__global__ void zero_ctr(int* __restrict__ ctr) {
  if (threadIdx.x == 0) ctr[0] = 0;
}

// ---------------- RoPE + RMSNorm + bucket codes + marginal-row flagging ----
__global__ __launch_bounds__(256) void rope_fused(float* __restrict__ Qb,
                                                  float* __restrict__ Kb,
                                                  const float* __restrict__ cosb,
                                                  const float* __restrict__ sinb,
                                                  const float* __restrict__ Wdq,
                                                  const float* __restrict__ Wdk,
                                                  int* __restrict__ qcodes,
                                                  int* __restrict__ kcodes,
                                                  int* __restrict__ wl,
                                                  int* __restrict__ ctr) {
  float* __restrict__ buf = blockIdx.y ? Kb : Qb;
  const float* __restrict__ Wd = blockIdx.y ? Wdk : Wdq;
  int* __restrict__ codes = blockIdx.y ? kcodes : qcodes;
  int wave = (blockIdx.x << 2) + (threadIdx.x >> 6);
  int lane = threadIdx.x & 63;
  int t = wave / NH, h = wave % NH;
  size_t base = (size_t)t * C + h * HD;
  float x1 = buf[base + lane];
  float x2 = buf[base + lane + 64];
  float c = cosb[t * 64 + lane];
  float s = sinb[t * 64 + lane];
  float r1 = x1 * c + x2 * s;
  float r2 = x2 * c - x1 * s;       // -x1*s + x2*c
  float ss = wave_sum(r1 * r1 + r2 * r2);
  float inv = 1.0f / sqrtf(ss * (1.0f / 128.0f) + 1e-6f);
  r1 *= inv; r2 *= inv;
  buf[base + lane] = r1;
  buf[base + lane + 64] = r2;
  int code = 0;
  bool marg = false;
  #pragma unroll
  for (int kk = 0; kk < 7; ++kk) {
    float z = r1 * Wd[kk * HD + lane] + r2 * Wd[kk * HD + lane + 64];
    z = wave_sum(z);
    float sig = 1.0f / (1.0f + expf(-z));
    float d = sig * 1.99f - 1.0f;
    if (d >= 0.f) code |= (1 << kk);
    marg |= (fabsf(d) < MARG);
  }
  if (lane == 0) {
    codes[h * T + t] = code;
    if (marg) {
      int i = atomicAdd(ctr, 1);
      if ((unsigned)i < (unsigned)WL_CAP) wl[i] = ((int)blockIdx.y << 15) | (h << 11) | t;
    }
  }
}

// ---------------- exact code recompute for marginal rows (FROZEN path) -----
__global__ __launch_bounds__(64) void fix_codes(const float* __restrict__ x,
                                                const float* __restrict__ Wq,
                                                const float* __restrict__ Wk,
                                                const float* __restrict__ cosb,
                                                const float* __restrict__ sinb,
                                                const float* __restrict__ Wdq,
                                                const float* __restrict__ Wdk,
                                                int* __restrict__ qc,
                                                int* __restrict__ kc,
                                                const int* __restrict__ wl,
                                                const int* __restrict__ ctr) {
  const int n = min(max(ctr[0], 0), WL_CAP);
  const int lane = threadIdx.x;
  for (int e = blockIdx.x; e < n; e += gridDim.x) {
    const int ent = wl[e];
    const int isK = (ent >> 15) & 1;
    const int h = (ent >> 11) & 15;
    const int t = ent & 2047;
    const float* __restrict__ W  = isK ? Wk : Wq;
    const float* __restrict__ Wd = isK ? Wdk : Wdq;
    int* __restrict__ codes = isK ? kc : qc;

    const float* xr = x + (size_t)t * C;
    const float* w0 = W + (size_t)(h * HD + lane) * C;
    const float* w1 = W + (size_t)(h * HD + lane + 64) * C;
    float p0[4] = {0.f, 0.f, 0.f, 0.f};
    float p1[4] = {0.f, 0.f, 0.f, 0.f};
    for (int k = 0; k < C; k += 4) {
      float4 xv = *(const float4*)(xr + k);
      float4 a = *(const float4*)(w0 + k);
      float4 b = *(const float4*)(w1 + k);
      p0[0] += xv.x * a.x; p0[1] += xv.y * a.y;
      p0[2] += xv.z * a.z; p0[3] += xv.w * a.w;
      p1[0] += xv.x * b.x; p1[1] += xv.y * b.y;
      p1[2] += xv.z * b.z; p1[3] += xv.w * b.w;
    }
    float x1 = (p0[0] + p0[1]) + (p0[2] + p0[3]);   // frozen merge
    float x2 = (p1[0] + p1[1]) + (p1[2] + p1[3]);
    float c = cosb[t * 64 + lane];
    float s = sinb[t * 64 + lane];
    float r1 = x1 * c + x2 * s;
    float r2 = x2 * c - x1 * s;
    float ss = wave_sum(r1 * r1 + r2 * r2);
    float inv = 1.0f / sqrtf(ss * (1.0f / 128.0f) + 1e-6f);
    r1 *= inv; r2 *= inv;
    int code = 0;
    #pragma unroll
    for (int kk = 0; kk < 7; ++kk) {
      float z = r1 * Wd[kk * HD + lane] + r2 * Wd[kk * HD + lane + 64];
      z = wave_sum(z);
      float sig = 1.0f / (1.0f + expf(-z));
      if (sig * 1.99f >= 1.0f) code |= (1 << kk);
    }
    if (lane == 0) codes[h * T + t] = code;
  }
}

// ---------------- sparse ballot-scan attention (validated) ---------------
__global__ __launch_bounds__(256) void attn_sparse(const float* __restrict__ Q,
                                                   const float* __restrict__ Kn,
                                                   const float* __restrict__ V,
                                                   const int* __restrict__ qc,
                                                   const int* __restrict__ kc,
                                                   float* __restrict__ Y) {
  const int tid = threadIdx.x;
  const int lane = tid & 63;
  const int wave_id = blockIdx.x * 4 + (tid >> 6);   // [0, T*NH)
  const int h = wave_id & (NH - 1);
  const int qrow = wave_id >> 4;
  const size_t hb = (size_t)h * HD;

  const float q0 = Q[(size_t)qrow * C + hb + lane];
  const float q1 = Q[(size_t)qrow * C + hb + lane + 64];
  const int qcode = qc[h * T + qrow];
  const int* kch = kc + h * T;

  float m = -1e30f, l = 0.f, acc0 = 0.f, acc1 = 0.f;

  const int nchunks = (qrow >> 6) + 1;
  int kcj = kch[lane];
  for (int ci = 0; ci < nchunks; ++ci) {
    const int j0 = ci << 6;
    const int cur = kcj;
    if (ci + 1 < nchunks) kcj = kch[j0 + 64 + lane];
    unsigned long long mask = __ballot((cur == qcode) && (j0 + lane <= qrow));
    while (mask) {
      const int j = j0 + (__ffsll((long long)mask) - 1);
      mask &= mask - 1;
      const float* kr = Kn + (size_t)j * C + hb;
      const float* vr = V + (size_t)j * C + hb;
      const float k0v = kr[lane], k1v = kr[lane + 64];
      const float v0 = vr[lane], v1 = vr[lane + 64];
      const float s = wave_sum(q0 * k0v + q1 * k1v) * SCALE;
      const float m_new = fmaxf(m, s);
      const float alpha = __expf(m - m_new);
      const float p = __expf(s - m_new);
      l = l * alpha + p;
      acc0 = acc0 * alpha + p * v0;
      acc1 = acc1 * alpha + p * v1;
      m = m_new;
    }
  }
  const float invl = (l > 0.f) ? 1.0f / l : 0.f;
  Y[(size_t)qrow * C + hb + lane] = acc0 * invl;
  Y[(size_t)qrow * C + hb + lane + 64] = acc1 * invl;
}

extern "C" void kernel_launch(void* const* d_in, const int* in_sizes, int n_in,
                              void* d_out, int out_size, void* d_ws, size_t ws_size,
                              hipStream_t stream) {
  (void)in_sizes; (void)n_in; (void)out_size;
  const float* x     = (const float*)d_in[0];
  const float* cosb  = (const float*)d_in[1];
  const float* sinb  = (const float*)d_in[2];
  const float* Wq    = (const float*)d_in[3];
  const float* Wk    = (const float*)d_in[4];
  const float* Wv    = (const float*)d_in[5];
  const float* Wproj = (const float*)d_in[6];
  const float* Wdq   = (const float*)d_in[7];
  const float* Wdk   = (const float*)d_in[8];
  float* out = (float*)d_out;

  const size_t MB = 1024 * 1024;
  char* ws = (char*)d_ws;
  const int n4 = T * C / 4;

  if (ws_size >= (size_t)64 * MB) {
    // ---- fast path, 64 MiB packed layout (liveness identical to round 9) --
    unsigned short* xh  = (unsigned short*)(ws);
    unsigned short* xl  = (unsigned short*)(ws + 8 * MB);
    unsigned short* wqh = (unsigned short*)(ws + 16 * MB);
    unsigned short* wql = (unsigned short*)(ws + 24 * MB);
    unsigned short* wkh = (unsigned short*)(ws + 32 * MB);
    unsigned short* wkl = (unsigned short*)(ws + 40 * MB);
    float* K = (float*)(ws + 48 * MB);
    unsigned short* wvh = (unsigned short*)(ws + 16 * MB);   // after QK gemm
    float* V = (float*)(ws + 24 * MB);                        // after QK gemm
    int* qc  = (int*)(ws + 40 * MB);                          // after QK gemm
    int* kc  = qc + NH * T;
    int* ctr = kc + NH * T;
    int* wl  = ctr + 16;
    float* Y = (float*)(ws);                                  // after V gemm
    unsigned short* yh  = (unsigned short*)(ws + 16 * MB);    // after attn
    unsigned short* wph = (unsigned short*)(ws + 24 * MB);    // after attn
    float* Q = out;                 // Q dead before proj overwrites d_out

    pre_split3<<<dim3(1024, 3), 256, 0, stream>>>(x, Wq, Wk, xh, xl, wqh, wql, wkh, wkl, n4);
    zero_ctr<<<1, 64, 0, stream>>>(ctr);   // AFTER wkl is fully written (stream order)
    gemm_qkf<<<dim3(T / 128, C / 64), 256, 0, stream>>>(xh, xl, wqh, wql, wkh, wkl, Q, K);
    to_f16h<<<2048, 256, 0, stream>>>(Wv, wvh, n4);           // wqh dead
    gemm_h1<<<dim3(T / 128, C / 128), 256, 0, stream>>>(xh, wvh, V);  // wql/wkh dead
    rope_fused<<<dim3(T * NH / 4, 2), 256, 0, stream>>>(Q, K, cosb, sinb, Wdq, Wdk, qc, kc, wl, ctr);
    fix_codes<<<256, 64, 0, stream>>>(x, Wq, Wk, cosb, sinb, Wdq, Wdk, qc, kc, wl, ctr);
    attn_sparse<<<T * NH / 4, 256, 0, stream>>>(Q, K, V, qc, kc, Y);  // xh/xl dead
    post_h2<<<dim3(1024, 2), 256, 0, stream>>>(Y, Wproj, yh, wph, n4); // wvh, V dead
    gemm_h1<<<dim3(T / 128, C / 128), 256, 0, stream>>>(yh, wph, out);
  } else {
    // ---- fallback: round-5 proven path (56.26 MiB layout) ----
    float* Kbuf = (float*)ws;
    float* V    = (float*)(ws + 16 * MB);
    float* Y    = (float*)(ws + 32 * MB);
    unsigned short* Wbf = (unsigned short*)(ws + 48 * MB);
    unsigned short* xbf = (unsigned short*)Y;
    unsigned short* Ybf = (unsigned short*)Kbuf;
    float* Q    = out;
    int* qc  = (int*)(Wbf + (size_t)T * C);
    int* kc  = qc + NH * T;
    int* ctr = kc + NH * T;
    int* wl  = ctr + 16;

    to_bf16<<<2048, 256, 0, stream>>>(x, xbf, n4);
    to_bf16<<<2048, 256, 0, stream>>>(Wv, Wbf, n4);
    gemm_bf16n<<<dim3(T / VBM, C / VBN), 256, 0, stream>>>(xbf, Wbf, V);
    gemm_qk_split16<<<dim3(T / SBM, C / SBN, 2), 256, 0, stream>>>(x, Wq, Wk, Q, Kbuf);
    zero_ctr<<<1, 64, 0, stream>>>(ctr);
    rope_fused<<<dim3(T * NH / 4, 2), 256, 0, stream>>>(Q, Kbuf, cosb, sinb, Wdq, Wdk, qc, kc, wl, ctr);
    fix_codes<<<256, 64, 0, stream>>>(x, Wq, Wk, cosb, sinb, Wdq, Wdk, qc, kc, wl, ctr);
    attn_sparse<<<T * NH / 4, 256, 0, stream>>>(Q, Kbuf, V, qc, kc, Y);
    to_bf16<<<2048, 256, 0, stream>>>(Y, Ybf, n4);
    to_bf16<<<2048, 256, 0, stream>>>(Wproj, Wbf, n4);
    gemm_bf16n<<<dim3(T / VBM, C / VBN), 256, 0, stream>>>(Ybf, Wbf, out);
  }
}

// Round 12
// 470.812 us; speedup vs baseline: 1.0289x; 1.0289x over previous
//
#include <hip/hip_runtime.h>
#include <hip/hip_bf16.h>
#include <math.h>

#define T 2048
#define C 2048
#define NH 16
#define HD 128
#define SCALE 0.08838834764831845f   // 1/sqrt(128)
#define WL_CAP 2048
#define MARG 1e-4f                    // |sig*1.99-1| margin ~ |z-z*|<2e-4

typedef short s16x8 __attribute__((ext_vector_type(8)));
typedef float f32x4 __attribute__((ext_vector_type(4)));
typedef _Float16 f16;
typedef f16 f16x8 __attribute__((ext_vector_type(8)));

__device__ __forceinline__ float wave_sum(float v) {
  #pragma unroll
  for (int o = 32; o > 0; o >>= 1) v += __shfl_xor(v, o, 64);
  return v;
}
// RNE fp32->bf16
__device__ __forceinline__ unsigned short f2bf(float f) {
  unsigned u = __float_as_uint(f);
  u += 0x7FFFu + ((u >> 16) & 1u);
  return (unsigned short)(u >> 16);
}

// ---------------- fp32 -> bf16 pre-convert (fallback path only) ----------
__global__ __launch_bounds__(256) void to_bf16(const float* __restrict__ in,
                                               unsigned short* __restrict__ outp,
                                               int n4) {
  int i = blockIdx.x * blockDim.x + threadIdx.x;
  const int stride = gridDim.x * blockDim.x;
  for (; i < n4; i += stride) {
    float4 v = ((const float4*)in)[i];
    ushort4 o;
    o.x = f2bf(v.x); o.y = f2bf(v.y); o.z = f2bf(v.z); o.w = f2bf(v.w);
    ((ushort4*)outp)[i] = o;
  }
}

// ---------------- shared split constants ----------------
#define PRESC 4096.0f               // 2^12
#define S0F 5.9604644775390625e-8f  // 2^-24
#define S1F 2.9103830456733704e-11f // 2^-35
#define S2F 1.4210854715202004e-14f // 2^-46

__device__ __forceinline__ void split4(float4 v, ushort4& hi, ushort4& lo) {
  float s0 = v.x * PRESC, s1 = v.y * PRESC, s2 = v.z * PRESC, s3 = v.w * PRESC;
  union { f16 h[4]; ushort4 u; } H, L;
  H.h[0] = (f16)s0; H.h[1] = (f16)s1; H.h[2] = (f16)s2; H.h[3] = (f16)s3;
  L.h[0] = (f16)((s0 - (float)H.h[0]) * 2048.0f);
  L.h[1] = (f16)((s1 - (float)H.h[1]) * 2048.0f);
  L.h[2] = (f16)((s2 - (float)H.h[2]) * 2048.0f);
  L.h[3] = (f16)((s3 - (float)H.h[3]) * 2048.0f);
  hi = H.u; lo = L.u;
}

// ---------------- fp32 -> fp16 hi/lo pre-split (fallback single) ----------
__global__ __launch_bounds__(256) void split_f16(const float* __restrict__ in,
                                                 unsigned short* __restrict__ hip_,
                                                 unsigned short* __restrict__ lop,
                                                 int n4) {
  int i = blockIdx.x * blockDim.x + threadIdx.x;
  const int stride = gridDim.x * blockDim.x;
  for (; i < n4; i += stride) {
    ushort4 h, l;
    split4(((const float4*)in)[i], h, l);
    ((ushort4*)hip_)[i] = h;
    ((ushort4*)lop)[i] = l;
  }
}

// ---------------- fused pre-split of x, Wq, Wk (1 launch) -----------------
// NOTE: does NOT touch ctr — ctr aliases the wkl region; it is zeroed later
// (inside to_f16h, which runs after gemm_qkf when wkl is dead).
__global__ __launch_bounds__(256) void pre_split3(const float* __restrict__ x,
                                                  const float* __restrict__ Wq,
                                                  const float* __restrict__ Wk,
                                                  unsigned short* __restrict__ xh,
                                                  unsigned short* __restrict__ xl,
                                                  unsigned short* __restrict__ wqh,
                                                  unsigned short* __restrict__ wql,
                                                  unsigned short* __restrict__ wkh,
                                                  unsigned short* __restrict__ wkl,
                                                  int n4) {
  const float* __restrict__ in;
  unsigned short *oh, *ol;
  if (blockIdx.y == 0)      { in = x;  oh = xh;  ol = xl;  }
  else if (blockIdx.y == 1) { in = Wq; oh = wqh; ol = wql; }
  else                      { in = Wk; oh = wkh; ol = wkl; }
  int i = blockIdx.x * blockDim.x + threadIdx.x;
  const int stride = gridDim.x * blockDim.x;
  for (; i < n4; i += stride) {
    ushort4 h, l;
    split4(((const float4*)in)[i], h, l);
    ((ushort4*)oh)[i] = h;
    ((ushort4*)ol)[i] = l;
  }
}

// ---------------- fp32 -> fp16 hi plane only (+ ctr zero, fused) ----------
// Runs after gemm_qkf (wkl dead) and before rope_fused => safe ctr home.
__global__ __launch_bounds__(256) void to_f16h(const float* __restrict__ in,
                                               unsigned short* __restrict__ outp,
                                               int* __restrict__ ctr,
                                               int n4) {
  if (ctr && blockIdx.x == 0 && threadIdx.x == 0) ctr[0] = 0;
  int i = blockIdx.x * blockDim.x + threadIdx.x;
  const int stride = gridDim.x * blockDim.x;
  for (; i < n4; i += stride) {
    float4 v = ((const float4*)in)[i];
    union { f16 h[4]; ushort4 u; } H;
    H.h[0] = (f16)(v.x * PRESC); H.h[1] = (f16)(v.y * PRESC);
    H.h[2] = (f16)(v.z * PRESC); H.h[3] = (f16)(v.w * PRESC);
    ((ushort4*)outp)[i] = H.u;
  }
}

// ---------------- fused tail convert: Y and Wproj to fp16-hi --------------
__global__ __launch_bounds__(256) void post_h2(const float* __restrict__ Y,
                                               const float* __restrict__ Wproj,
                                               unsigned short* __restrict__ yh,
                                               unsigned short* __restrict__ wph,
                                               int n4) {
  const float* __restrict__ in = blockIdx.y ? Wproj : Y;
  unsigned short* __restrict__ outp = blockIdx.y ? wph : yh;
  int i = blockIdx.x * blockDim.x + threadIdx.x;
  const int stride = gridDim.x * blockDim.x;
  for (; i < n4; i += stride) {
    float4 v = ((const float4*)in)[i];
    union { f16 h[4]; ushort4 u; } H;
    H.h[0] = (f16)(v.x * PRESC); H.h[1] = (f16)(v.y * PRESC);
    H.h[2] = (f16)(v.z * PRESC); H.h[3] = (f16)(v.w * PRESC);
    ((ushort4*)outp)[i] = H.u;
  }
}

#define SBM 64
#define SBN 128
#define SBK 32

// ---------------- fused Q+K GEMM, 128x(64|64) tile, A shared --------------
// ROUND-9 PROVEN FORM (reg-staged; gload_lds variant measured SLOWER r11).
// B-tile = [64 cols of Wq | 64 cols of Wk]; waves (wm in M) x (wn: 0=Q,1=K),
// each 64x64 out (mi=ni=4). 48 MFMA per 24 LDS ops per wave.
__global__ __launch_bounds__(256, 2) void gemm_qkf(const unsigned short* __restrict__ xhp,
                                                   const unsigned short* __restrict__ xlp,
                                                   const unsigned short* __restrict__ wqh,
                                                   const unsigned short* __restrict__ wql,
                                                   const unsigned short* __restrict__ wkh,
                                                   const unsigned short* __restrict__ wkl,
                                                   float* __restrict__ Qo,
                                                   float* __restrict__ Ko) {
  __shared__ unsigned short Ah[2][128 * 32];   // 2 x 8 KB
  __shared__ unsigned short Av[2][128 * 32];
  __shared__ unsigned short Bh[2][128 * 32];   // rows 0-63 = Wq, 64-127 = Wk
  __shared__ unsigned short Bv[2][128 * 32];   // 64 KB total
  const int tid = threadIdx.x;
  const int bm = blockIdx.x * 128;
  const int bn = blockIdx.y * 64;      // col offset within each weight
  const int wv = tid >> 6, lane = tid & 63;
  const int wm = wv & 1, wn = wv >> 1;  // wn: 0=Q, 1=K
  const int lrow = lane & 15, lquad = lane >> 4;

  const int sr = tid >> 2, qg = tid & 3;
  const int qs = qg ^ ((sr >> 1) & 3);   // same swz for row sr and 64+sr

  f32x4 acc0[4][4], acc1[4][4];
  #pragma unroll
  for (int i = 0; i < 4; ++i)
    #pragma unroll
    for (int j = 0; j < 4; ++j) {
      acc0[i][j] = (f32x4){0.f, 0.f, 0.f, 0.f};
      acc1[i][j] = (f32x4){0.f, 0.f, 0.f, 0.f};
    }

  // prologue: stage iter 0 into buffer 0
  {
    uint4 a0H = *(const uint4*)(xhp + (size_t)(bm + sr) * C + qg * 8);
    uint4 a0L = *(const uint4*)(xlp + (size_t)(bm + sr) * C + qg * 8);
    uint4 a1H = *(const uint4*)(xhp + (size_t)(bm + 64 + sr) * C + qg * 8);
    uint4 a1L = *(const uint4*)(xlp + (size_t)(bm + 64 + sr) * C + qg * 8);
    uint4 bqH = *(const uint4*)(wqh + (size_t)(bn + sr) * C + qg * 8);
    uint4 bqL = *(const uint4*)(wql + (size_t)(bn + sr) * C + qg * 8);
    uint4 bkH = *(const uint4*)(wkh + (size_t)(bn + sr) * C + qg * 8);
    uint4 bkL = *(const uint4*)(wkl + (size_t)(bn + sr) * C + qg * 8);
    *(uint4*)&Ah[0][sr * 32 + qs * 8] = a0H;
    *(uint4*)&Av[0][sr * 32 + qs * 8] = a0L;
    *(uint4*)&Ah[0][(64 + sr) * 32 + qs * 8] = a1H;
    *(uint4*)&Av[0][(64 + sr) * 32 + qs * 8] = a1L;
    *(uint4*)&Bh[0][sr * 32 + qs * 8] = bqH;
    *(uint4*)&Bv[0][sr * 32 + qs * 8] = bqL;
    *(uint4*)&Bh[0][(64 + sr) * 32 + qs * 8] = bkH;
    *(uint4*)&Bv[0][(64 + sr) * 32 + qs * 8] = bkL;
  }
  __syncthreads();

  const int niter = C / 32;
  for (int it = 0; it < niter; ++it) {
    const int cur = it & 1;
    const bool has = (it + 1) < niter;
    uint4 a0H, a0L, a1H, a1L, bqH, bqL, bkH, bkL;
    if (has) {
      const int k0 = (it + 1) * 32;
      a0H = *(const uint4*)(xhp + (size_t)(bm + sr) * C + k0 + qg * 8);
      a0L = *(const uint4*)(xlp + (size_t)(bm + sr) * C + k0 + qg * 8);
      a1H = *(const uint4*)(xhp + (size_t)(bm + 64 + sr) * C + k0 + qg * 8);
      a1L = *(const uint4*)(xlp + (size_t)(bm + 64 + sr) * C + k0 + qg * 8);
      bqH = *(const uint4*)(wqh + (size_t)(bn + sr) * C + k0 + qg * 8);
      bqL = *(const uint4*)(wql + (size_t)(bn + sr) * C + k0 + qg * 8);
      bkH = *(const uint4*)(wkh + (size_t)(bn + sr) * C + k0 + qg * 8);
      bkL = *(const uint4*)(wkl + (size_t)(bn + sr) * C + k0 + qg * 8);
    }
    f16x8 ah[4], av[4], bh[4], bv[4];
    #pragma unroll
    for (int mi = 0; mi < 4; ++mi) {
      const int r = wm * 64 + mi * 16 + lrow;
      const int q = lquad ^ ((r >> 1) & 3);
      ah[mi] = *(const f16x8*)&Ah[cur][r * 32 + q * 8];
      av[mi] = *(const f16x8*)&Av[cur][r * 32 + q * 8];
    }
    #pragma unroll
    for (int ni = 0; ni < 4; ++ni) {
      const int r = wn * 64 + ni * 16 + lrow;
      const int q = lquad ^ ((r >> 1) & 3);
      bh[ni] = *(const f16x8*)&Bh[cur][r * 32 + q * 8];
      bv[ni] = *(const f16x8*)&Bv[cur][r * 32 + q * 8];
    }
    #pragma unroll
    for (int mi = 0; mi < 4; ++mi)
      #pragma unroll
      for (int ni = 0; ni < 4; ++ni) {
        acc0[mi][ni] = __builtin_amdgcn_mfma_f32_16x16x32_f16(ah[mi], bh[ni], acc0[mi][ni], 0, 0, 0);
        acc1[mi][ni] = __builtin_amdgcn_mfma_f32_16x16x32_f16(ah[mi], bv[ni], acc1[mi][ni], 0, 0, 0);
        acc1[mi][ni] = __builtin_amdgcn_mfma_f32_16x16x32_f16(av[mi], bh[ni], acc1[mi][ni], 0, 0, 0);
      }
    if (has) {
      const int nxt = cur ^ 1;
      *(uint4*)&Ah[nxt][sr * 32 + qs * 8] = a0H;
      *(uint4*)&Av[nxt][sr * 32 + qs * 8] = a0L;
      *(uint4*)&Ah[nxt][(64 + sr) * 32 + qs * 8] = a1H;
      *(uint4*)&Av[nxt][(64 + sr) * 32 + qs * 8] = a1L;
      *(uint4*)&Bh[nxt][sr * 32 + qs * 8] = bqH;
      *(uint4*)&Bv[nxt][sr * 32 + qs * 8] = bqL;
      *(uint4*)&Bh[nxt][(64 + sr) * 32 + qs * 8] = bkH;
      *(uint4*)&Bv[nxt][(64 + sr) * 32 + qs * 8] = bkL;
    }
    __syncthreads();
  }
  // epilogue: C/D layout col=lane&15, row=lquad*4+r (m89-verified)
  float* __restrict__ Cc = wn ? Ko : Qo;
  #pragma unroll
  for (int mi = 0; mi < 4; ++mi)
    #pragma unroll
    for (int ni = 0; ni < 4; ++ni)
      #pragma unroll
      for (int r = 0; r < 4; ++r) {
        int row = bm + wm * 64 + mi * 16 + lquad * 4 + r;
        int col = bn + ni * 16 + lrow;
        Cc[(size_t)row * C + col] = acc0[mi][ni][r] * S0F + acc1[mi][ni][r] * S1F;
      }
}

// ---------------- 1-term fp16-hi GEMM (V and proj; smooth paths) ----------
// ROUND-9 PROVEN FORM: 64x128 tile, reg-staged, 2 blocks/CU.
__global__ __launch_bounds__(256) void gemm_h1(const unsigned short* __restrict__ A,
                                               const unsigned short* __restrict__ B,
                                               float* __restrict__ Cc) {
  __shared__ unsigned short Ah[2][SBM * SBK];   // 2 x 4 KB
  __shared__ unsigned short Bh[2][SBN * SBK];   // 2 x 8 KB  (24 KB)
  const int tid = threadIdx.x;
  const int bm = blockIdx.x * SBM;
  const int bn = blockIdx.y * SBN;
  const int wv = tid >> 6, lane = tid & 63;
  const int wm = wv & 1, wn = wv >> 1;
  const int lrow = lane & 15, lquad = lane >> 4;

  const int a_row = tid >> 2, qg = tid & 3;
  const int a_qs = qg ^ ((a_row >> 1) & 3);
  const int b_row0 = tid >> 2;
  const int b_qs = qg ^ ((b_row0 >> 1) & 3);

  f32x4 acc[2][4];
  #pragma unroll
  for (int i = 0; i < 2; ++i)
    #pragma unroll
    for (int j = 0; j < 4; ++j) acc[i][j] = (f32x4){0.f, 0.f, 0.f, 0.f};

  {
    uint4 av = *(const uint4*)(A + (size_t)(bm + a_row) * C + qg * 8);
    uint4 b0 = *(const uint4*)(B + (size_t)(bn + b_row0) * C + qg * 8);
    uint4 b1 = *(const uint4*)(B + (size_t)(bn + 64 + b_row0) * C + qg * 8);
    *(uint4*)&Ah[0][a_row * SBK + a_qs * 8] = av;
    *(uint4*)&Bh[0][b_row0 * SBK + b_qs * 8] = b0;
    *(uint4*)&Bh[0][(64 + b_row0) * SBK + b_qs * 8] = b1;
  }
  __syncthreads();

  const int niter = C / SBK;
  for (int it = 0; it < niter; ++it) {
    const int cur = it & 1;
    const bool has = (it + 1) < niter;
    uint4 avn, b0n, b1n;
    if (has) {
      const int k0 = (it + 1) * SBK;
      avn = *(const uint4*)(A + (size_t)(bm + a_row) * C + k0 + qg * 8);
      b0n = *(const uint4*)(B + (size_t)(bn + b_row0) * C + k0 + qg * 8);
      b1n = *(const uint4*)(B + (size_t)(bn + 64 + b_row0) * C + k0 + qg * 8);
    }
    f16x8 af[2], bfr[4];
    #pragma unroll
    for (int mi = 0; mi < 2; ++mi) {
      const int r = wm * 32 + mi * 16 + lrow;
      const int q = lquad ^ ((r >> 1) & 3);
      af[mi] = *(const f16x8*)&Ah[cur][r * SBK + q * 8];
    }
    #pragma unroll
    for (int ni = 0; ni < 4; ++ni) {
      const int r = wn * 64 + ni * 16 + lrow;
      const int q = lquad ^ ((r >> 1) & 3);
      bfr[ni] = *(const f16x8*)&Bh[cur][r * SBK + q * 8];
    }
    #pragma unroll
    for (int mi = 0; mi < 2; ++mi)
      #pragma unroll
      for (int ni = 0; ni < 4; ++ni)
        acc[mi][ni] = __builtin_amdgcn_mfma_f32_16x16x32_f16(af[mi], bfr[ni], acc[mi][ni], 0, 0, 0);
    if (has) {
      const int nxt = cur ^ 1;
      *(uint4*)&Ah[nxt][a_row * SBK + a_qs * 8] = avn;
      *(uint4*)&Bh[nxt][b_row0 * SBK + b_qs * 8] = b0n;
      *(uint4*)&Bh[nxt][(64 + b_row0) * SBK + b_qs * 8] = b1n;
    }
    __syncthreads();
  }
  #pragma unroll
  for (int mi = 0; mi < 2; ++mi)
    #pragma unroll
    for (int ni = 0; ni < 4; ++ni)
      #pragma unroll
      for (int r = 0; r < 4; ++r) {
        int row = bm + wm * 32 + mi * 16 + lquad * 4 + r;
        int col = bn + wn * 64 + ni * 16 + lrow;
        Cc[(size_t)row * C + col] = acc[mi][ni][r] * S0F;
      }
}

// ---------------- Q/K GEMM with IN-KERNEL split (round-5 fallback) --------
__device__ __forceinline__ void split8(const float4 v0, const float4 v1,
                                       uint4& hi, uint4& lo) {
  float s[8] = {v0.x * PRESC, v0.y * PRESC, v0.z * PRESC, v0.w * PRESC,
                v1.x * PRESC, v1.y * PRESC, v1.z * PRESC, v1.w * PRESC};
  union { uint4 u; f16 h[8]; } H, L;
  #pragma unroll
  for (int i = 0; i < 8; ++i) {
    f16 h2 = (f16)s[i];
    float d = s[i] - (float)h2;
    H.h[i] = h2;
    L.h[i] = (f16)(d * 2048.0f);
  }
  hi = H.u; lo = L.u;
}

__global__ __launch_bounds__(256, 2) void gemm_qk_split16(const float* __restrict__ A,
                                                          const float* __restrict__ Wq,
                                                          const float* __restrict__ Wk,
                                                          float* __restrict__ Qo,
                                                          float* __restrict__ Ko) {
  const float* __restrict__ Bw = blockIdx.z ? Wk : Wq;
  float* __restrict__ Cc = blockIdx.z ? Ko : Qo;
  __shared__ unsigned short Ah[2][SBM * SBK];
  __shared__ unsigned short Av[2][SBM * SBK];
  __shared__ unsigned short Bh[2][SBN * SBK];
  __shared__ unsigned short Bv[2][SBN * SBK];
  const int tid = threadIdx.x;
  const int bm = blockIdx.x * SBM;
  const int bn = blockIdx.y * SBN;
  const int wv = tid >> 6, lane = tid & 63;
  const int wm = wv & 1, wn = wv >> 1;
  const int lrow = lane & 15, lquad = lane >> 4;

  const int a_row = tid >> 2, qg = tid & 3;
  const int a_qs = qg ^ ((a_row >> 1) & 3);
  const int b_row0 = tid >> 2;
  const int b_qs = qg ^ ((b_row0 >> 1) & 3);

  f32x4 acc[3][2][4];
  #pragma unroll
  for (int g = 0; g < 3; ++g)
    #pragma unroll
    for (int i = 0; i < 2; ++i)
      #pragma unroll
      for (int j = 0; j < 4; ++j) acc[g][i][j] = (f32x4){0.f, 0.f, 0.f, 0.f};

  {
    const float* pA  = A  + (size_t)(bm + a_row) * C + qg * 8;
    const float* pB0 = Bw + (size_t)(bn + b_row0) * C + qg * 8;
    const float* pB1 = Bw + (size_t)(bn + 64 + b_row0) * C + qg * 8;
    uint4 h, l;
    split8(*(const float4*)pA, *(const float4*)(pA + 4), h, l);
    *(uint4*)&Ah[0][a_row * SBK + a_qs * 8] = h;
    *(uint4*)&Av[0][a_row * SBK + a_qs * 8] = l;
    split8(*(const float4*)pB0, *(const float4*)(pB0 + 4), h, l);
    *(uint4*)&Bh[0][b_row0 * SBK + b_qs * 8] = h;
    *(uint4*)&Bv[0][b_row0 * SBK + b_qs * 8] = l;
    split8(*(const float4*)pB1, *(const float4*)(pB1 + 4), h, l);
    *(uint4*)&Bh[0][(64 + b_row0) * SBK + b_qs * 8] = h;
    *(uint4*)&Bv[0][(64 + b_row0) * SBK + b_qs * 8] = l;
  }
  __syncthreads();

  const int niter = C / SBK;
  for (int it = 0; it < niter; ++it) {
    const int cur = it & 1;
    const bool has = (it + 1) < niter;
    float4 a0n, a1n, b00n, b01n, b10n, b11n;
    if (has) {
      const int k0 = (it + 1) * SBK;
      const float* pA  = A  + (size_t)(bm + a_row) * C + k0 + qg * 8;
      const float* pB0 = Bw + (size_t)(bn + b_row0) * C + k0 + qg * 8;
      const float* pB1 = Bw + (size_t)(bn + 64 + b_row0) * C + k0 + qg * 8;
      a0n = *(const float4*)pA;   a1n = *(const float4*)(pA + 4);
      b00n = *(const float4*)pB0; b01n = *(const float4*)(pB0 + 4);
      b10n = *(const float4*)pB1; b11n = *(const float4*)(pB1 + 4);
    }
    f16x8 ah[2], av[2], bh[4], bv[4];
    #pragma unroll
    for (int mi = 0; mi < 2; ++mi) {
      const int r = wm * 32 + mi * 16 + lrow;
      const int q = lquad ^ ((r >> 1) & 3);
      ah[mi] = *(const f16x8*)&Ah[cur][r * SBK + q * 8];
      av[mi] = *(const f16x8*)&Av[cur][r * SBK + q * 8];
    }
    #pragma unroll
    for (int ni = 0; ni < 4; ++ni) {
      const int r = wn * 64 + ni * 16 + lrow;
      const int q = lquad ^ ((r >> 1) & 3);
      bh[ni] = *(const f16x8*)&Bh[cur][r * SBK + q * 8];
      bv[ni] = *(const f16x8*)&Bv[cur][r * SBK + q * 8];
    }
    #pragma unroll
    for (int mi = 0; mi < 2; ++mi)
      #pragma unroll
      for (int ni = 0; ni < 4; ++ni) {
        acc[0][mi][ni] = __builtin_amdgcn_mfma_f32_16x16x32_f16(ah[mi], bh[ni], acc[0][mi][ni], 0, 0, 0);
        acc[1][mi][ni] = __builtin_amdgcn_mfma_f32_16x16x32_f16(ah[mi], bv[ni], acc[1][mi][ni], 0, 0, 0);
        acc[1][mi][ni] = __builtin_amdgcn_mfma_f32_16x16x32_f16(av[mi], bh[ni], acc[1][mi][ni], 0, 0, 0);
        acc[2][mi][ni] = __builtin_amdgcn_mfma_f32_16x16x32_f16(av[mi], bv[ni], acc[2][mi][ni], 0, 0, 0);
      }
    if (has) {
      const int nxt = cur ^ 1;
      uint4 h, l;
      split8(a0n, a1n, h, l);
      *(uint4*)&Ah[nxt][a_row * SBK + a_qs * 8] = h;
      *(uint4*)&Av[nxt][a_row * SBK + a_qs * 8] = l;
      split8(b00n, b01n, h, l);
      *(uint4*)&Bh[nxt][b_row0 * SBK + b_qs * 8] = h;
      *(uint4*)&Bv[nxt][b_row0 * SBK + b_qs * 8] = l;
      split8(b10n, b11n, h, l);
      *(uint4*)&Bh[nxt][(64 + b_row0) * SBK + b_qs * 8] = h;
      *(uint4*)&Bv[nxt][(64 + b_row0) * SBK + b_qs * 8] = l;
    }
    __syncthreads();
  }
  #pragma unroll
  for (int mi = 0; mi < 2; ++mi)
    #pragma unroll
    for (int ni = 0; ni < 4; ++ni)
      #pragma unroll
      for (int r = 0; r < 4; ++r) {
        int row = bm + wm * 32 + mi * 16 + lquad * 4 + r;
        int col = bn + wn * 64 + ni * 16 + lrow;
        float v = acc[0][mi][ni][r] * S0F + (acc[1][mi][ni][r] * S1F + acc[2][mi][ni][r] * S2F);
        Cc[(size_t)row * C + col] = v;
      }
}

// ---------------- bf16 MFMA GEMM (fallback path only) ---------------------
#define VBM 64
#define VBN 128
#define VBK 32

__global__ __launch_bounds__(256) void gemm_bf16n(const unsigned short* __restrict__ A,
                                                  const unsigned short* __restrict__ B,
                                                  float* __restrict__ Cc) {
  __shared__ unsigned short Al[2][VBM * VBK];
  __shared__ unsigned short Bl[2][VBN * VBK];
  const int tid = threadIdx.x;
  const int bm = blockIdx.x * VBM;
  const int bn = blockIdx.y * VBN;
  const int wv = tid >> 6, lane = tid & 63;
  const int wm = wv & 1, wn = wv >> 1;
  const int lrow = lane & 15, lquad = lane >> 4;

  const int a_row = tid >> 2, qg = tid & 3;
  const int a_qs = qg ^ ((a_row >> 1) & 3);
  const int b_row0 = tid >> 2;
  const int b_qs = qg ^ ((b_row0 >> 1) & 3);

  f32x4 acc[2][4];
  #pragma unroll
  for (int i = 0; i < 2; ++i)
    #pragma unroll
    for (int j = 0; j < 4; ++j) acc[i][j] = (f32x4){0.f, 0.f, 0.f, 0.f};

  {
    uint4 av = *(const uint4*)(A + (size_t)(bm + a_row) * C + qg * 8);
    uint4 b0 = *(const uint4*)(B + (size_t)(bn + b_row0) * C + qg * 8);
    uint4 b1 = *(const uint4*)(B + (size_t)(bn + 64 + b_row0) * C + qg * 8);
    *(uint4*)&Al[0][a_row * VBK + a_qs * 8] = av;
    *(uint4*)&Bl[0][b_row0 * VBK + b_qs * 8] = b0;
    *(uint4*)&Bl[0][(64 + b_row0) * VBK + b_qs * 8] = b1;
  }
  __syncthreads();

  const int niter = C / VBK;
  for (int it = 0; it < niter; ++it) {
    const int cur = it & 1;
    const bool has = (it + 1) < niter;
    uint4 avn, b0n, b1n;
    if (has) {
      const int k0 = (it + 1) * VBK;
      avn = *(const uint4*)(A + (size_t)(bm + a_row) * C + k0 + qg * 8);
      b0n = *(const uint4*)(B + (size_t)(bn + b_row0) * C + k0 + qg * 8);
      b1n = *(const uint4*)(B + (size_t)(bn + 64 + b_row0) * C + k0 + qg * 8);
    }
    s16x8 af[2], bfr[4];
    #pragma unroll
    for (int mi = 0; mi < 2; ++mi) {
      const int r = wm * 32 + mi * 16 + lrow;
      const int q = lquad ^ ((r >> 1) & 3);
      af[mi] = *(const s16x8*)&Al[cur][r * VBK + q * 8];
    }
    #pragma unroll
    for (int ni = 0; ni < 4; ++ni) {
      const int r = wn * 64 + ni * 16 + lrow;
      const int q = lquad ^ ((r >> 1) & 3);
      bfr[ni] = *(const s16x8*)&Bl[cur][r * VBK + q * 8];
    }
    #pragma unroll
    for (int mi = 0; mi < 2; ++mi)
      #pragma unroll
      for (int ni = 0; ni < 4; ++ni)
        acc[mi][ni] = __builtin_amdgcn_mfma_f32_16x16x32_bf16(af[mi], bfr[ni], acc[mi][ni], 0, 0, 0);
    if (has) {
      const int nxt = cur ^ 1;
      *(uint4*)&Al[nxt][a_row * VBK + a_qs * 8] = avn;
      *(uint4*)&Bl[nxt][b_row0 * VBK + b_qs * 8] = b0n;
      *(uint4*)&Bl[nxt][(64 + b_row0) * VBK + b_qs * 8] = b1n;
    }
    __syncthreads();
  }
  #pragma unroll
  for (int mi = 0; mi < 2; ++mi)
    #pragma unroll
    for (int ni = 0; ni < 4; ++ni)
      #pragma unroll
      for (int r = 0; r < 4; ++r) {
        int row = bm + wm * 32 + mi * 16 + lquad * 4 + r;
        int col = bn + wn * 64 + ni * 16 + lrow;
        Cc[(size_t)row * C + col] = acc[mi][ni][r];
      }
}

// ---------------- zero worklist counter (fallback path only) --------------
__global__ void zero_ctr(int* __restrict__ ctr) {
  if (threadIdx.x == 0) ctr[0] = 0;
}

// ---------------- RoPE + RMSNorm + bucket codes + marginal-row flagging ----
__global__ __launch_bounds__(256) void rope_fused(float* __restrict__ Qb,
                                                  float* __restrict__ Kb,
                                                  const float* __restrict__ cosb,
                                                  const float* __restrict__ sinb,
                                                  const float* __restrict__ Wdq,
                                                  const float* __restrict__ Wdk,
                                                  int* __restrict__ qcodes,
                                                  int* __restrict__ kcodes,
                                                  int* __restrict__ wl,
                                                  int* __restrict__ ctr) {
  float* __restrict__ buf = blockIdx.y ? Kb : Qb;
  const float* __restrict__ Wd = blockIdx.y ? Wdk : Wdq;
  int* __restrict__ codes = blockIdx.y ? kcodes : qcodes;
  int wave = (blockIdx.x << 2) + (threadIdx.x >> 6);
  int lane = threadIdx.x & 63;
  int t = wave / NH, h = wave % NH;
  size_t base = (size_t)t * C + h * HD;
  float x1 = buf[base + lane];
  float x2 = buf[base + lane + 64];
  float c = cosb[t * 64 + lane];
  float s = sinb[t * 64 + lane];
  float r1 = x1 * c + x2 * s;
  float r2 = x2 * c - x1 * s;       // -x1*s + x2*c
  float ss = wave_sum(r1 * r1 + r2 * r2);
  float inv = 1.0f / sqrtf(ss * (1.0f / 128.0f) + 1e-6f);
  r1 *= inv; r2 *= inv;
  buf[base + lane] = r1;
  buf[base + lane + 64] = r2;
  int code = 0;
  bool marg = false;
  #pragma unroll
  for (int kk = 0; kk < 7; ++kk) {
    float z = r1 * Wd[kk * HD + lane] + r2 * Wd[kk * HD + lane + 64];
    z = wave_sum(z);
    float sig = 1.0f / (1.0f + expf(-z));
    float d = sig * 1.99f - 1.0f;
    if (d >= 0.f) code |= (1 << kk);
    marg |= (fabsf(d) < MARG);
  }
  if (lane == 0) {
    codes[h * T + t] = code;
    if (marg) {
      int i = atomicAdd(ctr, 1);
      if ((unsigned)i < (unsigned)WL_CAP) wl[i] = ((int)blockIdx.y << 15) | (h << 11) | t;
    }
  }
}

// ---------------- exact code recompute for marginal rows (FROZEN path) -----
__global__ __launch_bounds__(64) void fix_codes(const float* __restrict__ x,
                                                const float* __restrict__ Wq,
                                                const float* __restrict__ Wk,
                                                const float* __restrict__ cosb,
                                                const float* __restrict__ sinb,
                                                const float* __restrict__ Wdq,
                                                const float* __restrict__ Wdk,
                                                int* __restrict__ qc,
                                                int* __restrict__ kc,
                                                const int* __restrict__ wl,
                                                const int* __restrict__ ctr) {
  const int n = min(max(ctr[0], 0), WL_CAP);
  const int lane = threadIdx.x;
  for (int e = blockIdx.x; e < n; e += gridDim.x) {
    const int ent = wl[e];
    const int isK = (ent >> 15) & 1;
    const int h = (ent >> 11) & 15;
    const int t = ent & 2047;
    const float* __restrict__ W  = isK ? Wk : Wq;
    const float* __restrict__ Wd = isK ? Wdk : Wdq;
    int* __restrict__ codes = isK ? kc : qc;

    const float* xr = x + (size_t)t * C;
    const float* w0 = W + (size_t)(h * HD + lane) * C;
    const float* w1 = W + (size_t)(h * HD + lane + 64) * C;
    float p0[4] = {0.f, 0.f, 0.f, 0.f};
    float p1[4] = {0.f, 0.f, 0.f, 0.f};
    for (int k = 0; k < C; k += 4) {
      float4 xv = *(const float4*)(xr + k);
      float4 a = *(const float4*)(w0 + k);
      float4 b = *(const float4*)(w1 + k);
      p0[0] += xv.x * a.x; p0[1] += xv.y * a.y;
      p0[2] += xv.z * a.z; p0[3] += xv.w * a.w;
      p1[0] += xv.x * b.x; p1[1] += xv.y * b.y;
      p1[2] += xv.z * b.z; p1[3] += xv.w * b.w;
    }
    float x1 = (p0[0] + p0[1]) + (p0[2] + p0[3]);   // frozen merge
    float x2 = (p1[0] + p1[1]) + (p1[2] + p1[3]);
    float c = cosb[t * 64 + lane];
    float s = sinb[t * 64 + lane];
    float r1 = x1 * c + x2 * s;
    float r2 = x2 * c - x1 * s;
    float ss = wave_sum(r1 * r1 + r2 * r2);
    float inv = 1.0f / sqrtf(ss * (1.0f / 128.0f) + 1e-6f);
    r1 *= inv; r2 *= inv;
    int code = 0;
    #pragma unroll
    for (int kk = 0; kk < 7; ++kk) {
      float z = r1 * Wd[kk * HD + lane] + r2 * Wd[kk * HD + lane + 64];
      z = wave_sum(z);
      float sig = 1.0f / (1.0f + expf(-z));
      if (sig * 1.99f >= 1.0f) code |= (1 << kk);
    }
    if (lane == 0) codes[h * T + t] = code;
  }
}

// ---------------- sparse ballot-scan attention, float2-vectorized ---------
// Lane holds elements 2*lane, 2*lane+1 of each 128-elem row (8B/lane loads).
// Reduction order changes vs round 9 — smooth path only (softmax); mask
// decisions are integer-exact. Halves VMEM instructions in the serial loop.
__global__ __launch_bounds__(256) void attn_sparse(const float* __restrict__ Q,
                                                   const float* __restrict__ Kn,
                                                   const float* __restrict__ V,
                                                   const int* __restrict__ qc,
                                                   const int* __restrict__ kc,
                                                   float* __restrict__ Y) {
  const int tid = threadIdx.x;
  const int lane = tid & 63;
  const int wave_id = blockIdx.x * 4 + (tid >> 6);   // [0, T*NH)
  const int h = wave_id & (NH - 1);
  const int qrow = wave_id >> 4;
  const size_t hb = (size_t)h * HD;

  const float2 qv = ((const float2*)(Q + (size_t)qrow * C + hb))[lane];
  const int qcode = qc[h * T + qrow];
  const int* kch = kc + h * T;

  float m = -1e30f, l = 0.f, acc0 = 0.f, acc1 = 0.f;

  const int nchunks = (qrow >> 6) + 1;
  int kcj = kch[lane];
  for (int ci = 0; ci < nchunks; ++ci) {
    const int j0 = ci << 6;
    const int cur = kcj;
    if (ci + 1 < nchunks) kcj = kch[j0 + 64 + lane];
    unsigned long long mask = __ballot((cur == qcode) && (j0 + lane <= qrow));
    while (mask) {
      const int j = j0 + (__ffsll((long long)mask) - 1);
      mask &= mask - 1;
      const float2 kv = ((const float2*)(Kn + (size_t)j * C + hb))[lane];
      const float2 vv = ((const float2*)(V + (size_t)j * C + hb))[lane];
      const float s = wave_sum(qv.x * kv.x + qv.y * kv.y) * SCALE;
      const float m_new = fmaxf(m, s);
      const float alpha = __expf(m - m_new);
      const float p = __expf(s - m_new);
      l = l * alpha + p;
      acc0 = acc0 * alpha + p * vv.x;
      acc1 = acc1 * alpha + p * vv.y;
      m = m_new;
    }
  }
  const float invl = (l > 0.f) ? 1.0f / l : 0.f;
  float2 o; o.x = acc0 * invl; o.y = acc1 * invl;
  ((float2*)(Y + (size_t)qrow * C + hb))[lane] = o;
}

extern "C" void kernel_launch(void* const* d_in, const int* in_sizes, int n_in,
                              void* d_out, int out_size, void* d_ws, size_t ws_size,
                              hipStream_t stream) {
  (void)in_sizes; (void)n_in; (void)out_size;
  const float* x     = (const float*)d_in[0];
  const float* cosb  = (const float*)d_in[1];
  const float* sinb  = (const float*)d_in[2];
  const float* Wq    = (const float*)d_in[3];
  const float* Wk    = (const float*)d_in[4];
  const float* Wv    = (const float*)d_in[5];
  const float* Wproj = (const float*)d_in[6];
  const float* Wdq   = (const float*)d_in[7];
  const float* Wdk   = (const float*)d_in[8];
  float* out = (float*)d_out;

  const size_t MB = 1024 * 1024;
  char* ws = (char*)d_ws;
  const int n4 = T * C / 4;

  if (ws_size >= (size_t)64 * MB) {
    // ---- fast path, 64 MiB packed layout (liveness identical to round 9) --
    unsigned short* xh  = (unsigned short*)(ws);
    unsigned short* xl  = (unsigned short*)(ws + 8 * MB);
    unsigned short* wqh = (unsigned short*)(ws + 16 * MB);
    unsigned short* wql = (unsigned short*)(ws + 24 * MB);
    unsigned short* wkh = (unsigned short*)(ws + 32 * MB);
    unsigned short* wkl = (unsigned short*)(ws + 40 * MB);
    float* K = (float*)(ws + 48 * MB);
    unsigned short* wvh = (unsigned short*)(ws + 16 * MB);   // after QK gemm
    float* V = (float*)(ws + 24 * MB);                        // after QK gemm
    int* qc  = (int*)(ws + 40 * MB);                          // after QK gemm
    int* kc  = qc + NH * T;
    int* ctr = kc + NH * T;
    int* wl  = ctr + 16;
    float* Y = (float*)(ws);                                  // after V gemm
    unsigned short* yh  = (unsigned short*)(ws + 16 * MB);    // after attn
    unsigned short* wph = (unsigned short*)(ws + 24 * MB);    // after attn
    float* Q = out;                 // Q dead before proj overwrites d_out

    pre_split3<<<dim3(1024, 3), 256, 0, stream>>>(x, Wq, Wk, xh, xl, wqh, wql, wkh, wkl, n4);
    gemm_qkf<<<dim3(T / 128, C / 64), 256, 0, stream>>>(xh, xl, wqh, wql, wkh, wkl, Q, K);
    to_f16h<<<2048, 256, 0, stream>>>(Wv, wvh, ctr, n4);      // wqh dead; zeroes ctr (wkl dead)
    gemm_h1<<<dim3(T / SBM, C / SBN), 256, 0, stream>>>(xh, wvh, V);  // wql/wkh dead
    rope_fused<<<dim3(T * NH / 4, 2), 256, 0, stream>>>(Q, K, cosb, sinb, Wdq, Wdk, qc, kc, wl, ctr);
    fix_codes<<<256, 64, 0, stream>>>(x, Wq, Wk, cosb, sinb, Wdq, Wdk, qc, kc, wl, ctr);
    attn_sparse<<<T * NH / 4, 256, 0, stream>>>(Q, K, V, qc, kc, Y);  // xh/xl dead
    post_h2<<<dim3(1024, 2), 256, 0, stream>>>(Y, Wproj, yh, wph, n4); // wvh, V dead
    gemm_h1<<<dim3(T / SBM, C / SBN), 256, 0, stream>>>(yh, wph, out);
  } else {
    // ---- fallback: round-5 proven path (56.26 MiB layout) ----
    float* Kbuf = (float*)ws;
    float* V    = (float*)(ws + 16 * MB);
    float* Y    = (float*)(ws + 32 * MB);
    unsigned short* Wbf = (unsigned short*)(ws + 48 * MB);
    unsigned short* xbf = (unsigned short*)Y;
    unsigned short* Ybf = (unsigned short*)Kbuf;
    float* Q    = out;
    int* qc  = (int*)(Wbf + (size_t)T * C);
    int* kc  = qc + NH * T;
    int* ctr = kc + NH * T;
    int* wl  = ctr + 16;

    to_bf16<<<2048, 256, 0, stream>>>(x, xbf, n4);
    to_bf16<<<2048, 256, 0, stream>>>(Wv, Wbf, n4);
    gemm_bf16n<<<dim3(T / VBM, C / VBN), 256, 0, stream>>>(xbf, Wbf, V);
    gemm_qk_split16<<<dim3(T / SBM, C / SBN, 2), 256, 0, stream>>>(x, Wq, Wk, Q, Kbuf);
    zero_ctr<<<1, 64, 0, stream>>>(ctr);
    rope_fused<<<dim3(T * NH / 4, 2), 256, 0, stream>>>(Q, Kbuf, cosb, sinb, Wdq, Wdk, qc, kc, wl, ctr);
    fix_codes<<<256, 64, 0, stream>>>(x, Wq, Wk, cosb, sinb, Wdq, Wdk, qc, kc, wl, ctr);
    attn_sparse<<<T * NH / 4, 256, 0, stream>>>(Q, Kbuf, V, qc, kc, Y);
    to_bf16<<<2048, 256, 0, stream>>>(Y, Ybf, n4);
    to_bf16<<<2048, 256, 0, stream>>>(Wproj, Wbf, n4);
    gemm_bf16n<<<dim3(T / VBM, C / VBN), 256, 0, stream>>>(Ybf, Wbf, out);
  }
}